// Round 1
// baseline (19.556 us; speedup 1.0000x reference)
//
#include <hip/hip_runtime.h>

#define NPART 64
#define NPTS 32768
#define BATCH 4

__global__ __launch_bounds__(256) void vortex_features_kernel(
    const float* __restrict__ inp,     // [B, NPART, 4] (y, x, tau, sig)
    const float* __restrict__ points,  // [B, NPTS, 2]  (py, px)
    float* __restrict__ out)           // [B, NPTS, 12]
{
    __shared__ float4 part[NPART];  // (y, x, tau, inv_sig2)

    const int b   = blockIdx.y;
    const int tid = threadIdx.x;

    if (tid < NPART) {
        float4 p = reinterpret_cast<const float4*>(inp)[b * NPART + tid];
        float inv_sig2 = 1.0f / (p.w * p.w);
        part[tid] = make_float4(p.x, p.y, p.z, inv_sig2);
    }
    __syncthreads();

    const int n = blockIdx.x * blockDim.x + tid;
    const float2 pt = reinterpret_cast<const float2*>(points)[b * NPTS + n];
    const float py = pt.x, px = pt.y;

    float f0 = 0.f, f1 = 0.f, f2 = 0.f, f3 = 0.f, f4 = 0.f;
    float f6 = 0.f, f7 = 0.f, f8 = 0.f, f9 = 0.f;

    #pragma unroll 8
    for (int i = 0; i < NPART; ++i) {
        float4 c = part[i];              // y, x, tau, inv_sig2 — LDS broadcast
        float dy = py - c.x;
        float dx = px - c.y;
        float q  = dy * dy + dx * dx;
        float inv_q = __builtin_amdgcn_rcpf(q);
        float rs    = __builtin_amdgcn_rsqf(q);
        float e     = __expf(-q * c.w);
        float g = c.z * e * rs;                          // strength * r (g = tau e / r)
        float a = -(c.w + 0.5f * inv_q);                 // g'/g
        float h = g * a;                                 // g'
        float k = g * (a * a + 0.5f * inv_q * inv_q);    // g''
        float h2 = h + h;
        float h6 = 6.0f * h;
        float k4 = 4.0f * k;
        float A = k4 * dy * dy;
        float B = k4 * dx * dx;

        f0 += g * dx;                 // v
        f1 -= g * dy;                 // u
        f2 += h2 * dy * dx;           // dv/dy
        f3 += h2 * dx * dx + g;       // dv/dx
        f4 -= h2 * dy * dy + g;       // du/dy
        f6 += dx * (A + h2);          // d2v/dy2
        f7 += dx * (B + h6);          // d2v/dx2
        f8 += dy * (B + h2);          // d2v/dxdy
        f9 -= dy * (A + h6);          // d2u/dy2
    }

    float4* o = reinterpret_cast<float4*>(out + (size_t)(b * NPTS + n) * 12);
    o[0] = make_float4(f0, f1, f2, f3);
    o[1] = make_float4(f4, -f2, f6, f7);     // du/dx = -dv/dy
    o[2] = make_float4(f8, f9, -f8, -f6);    // d2u/dx2 = -d2v/dxdy, d2u/dydx = -d2v/dy2
}

extern "C" void kernel_launch(void* const* d_in, const int* in_sizes, int n_in,
                              void* d_out, int out_size, void* d_ws, size_t ws_size,
                              hipStream_t stream) {
    const float* inp    = (const float*)d_in[0];
    const float* points = (const float*)d_in[1];
    float* out          = (float*)d_out;

    dim3 grid(NPTS / 256, BATCH);
    dim3 block(256);
    vortex_features_kernel<<<grid, block, 0, stream>>>(inp, points, out);
}

// Round 2
// 16.181 us; speedup vs baseline: 1.2086x; 1.2086x over previous
//
#include <hip/hip_runtime.h>

#define NPART 64
#define NPTS 32768
#define BATCH 4
#define SPLIT 4                 // threads per point
#define PPT (NPART / SPLIT)     // particles per thread = 16

__global__ __launch_bounds__(256, 8) void vortex_features_kernel(
    const float* __restrict__ inp,     // [B, NPART, 4] (y, x, tau, sig)
    const float* __restrict__ points,  // [B, NPTS, 2]  (py, px)
    float* __restrict__ out)           // [B, NPTS, 12]
{
    __shared__ float4 part[NPART];  // (y, x, tau, inv_sig2)

    const int b   = blockIdx.y;
    const int tid = threadIdx.x;

    if (tid < NPART) {
        float4 p = reinterpret_cast<const float4*>(inp)[b * NPART + tid];
        float inv_sig2 = 1.0f / (p.w * p.w);
        part[tid] = make_float4(p.x, p.y, p.z, inv_sig2);
    }
    __syncthreads();

    const int n   = blockIdx.x * (256 / SPLIT) + (tid >> 2);  // point index
    const int sub = tid & (SPLIT - 1);                        // particle-chunk index

    const float2 pt = reinterpret_cast<const float2*>(points)[b * NPTS + n];
    const float py = pt.x, px = pt.y;

    float f0 = 0.f, f1 = 0.f, f2 = 0.f, f3 = 0.f, f4 = 0.f;
    float f6 = 0.f, f7 = 0.f, f8 = 0.f, f9 = 0.f;

    #pragma unroll 4
    for (int ii = 0; ii < PPT; ++ii) {
        // interleaved: 4-lane group reads 4 consecutive float4s (64B) -> conflict-free
        float4 c = part[ii * SPLIT + sub];
        float dy = py - c.x;
        float dx = px - c.y;
        float dy2 = dy * dy;
        float dx2 = dx * dx;
        float q  = dy2 + dx2;
        float inv_q = __builtin_amdgcn_rcpf(q);
        float rs    = __builtin_amdgcn_rsqf(q);
        float e     = __expf(-q * c.w);
        float g = c.z * e * rs;                          // g = tau e / r
        float a = -(c.w + 0.5f * inv_q);                 // g'/g
        float h = g * a;                                 // g'
        float k = g * (a * a + 0.5f * inv_q * inv_q);    // g''
        float h2 = h + h;
        float h6 = 6.0f * h;
        float k4 = 4.0f * k;
        float A = k4 * dy2;
        float B = k4 * dx2;

        f0 += g * dx;                 // v
        f1 -= g * dy;                 // u
        f2 += h2 * dy * dx;           // dv/dy
        f3 += h2 * dx2 + g;           // dv/dx
        f4 -= h2 * dy2 + g;           // du/dy
        f6 += dx * (A + h2);          // d2v/dy2
        f7 += dx * (B + h6);          // d2v/dx2
        f8 += dy * (B + h2);          // d2v/dxdy
        f9 -= dy * (A + h6);          // d2u/dy2
    }

    // reduce across the 4 lanes sharing a point (butterfly, stays in-wave)
    #pragma unroll
    for (int m = 1; m <= 2; m <<= 1) {
        f0 += __shfl_xor(f0, m);
        f1 += __shfl_xor(f1, m);
        f2 += __shfl_xor(f2, m);
        f3 += __shfl_xor(f3, m);
        f4 += __shfl_xor(f4, m);
        f6 += __shfl_xor(f6, m);
        f7 += __shfl_xor(f7, m);
        f8 += __shfl_xor(f8, m);
        f9 += __shfl_xor(f9, m);
    }

    if (sub == 0) {
        float4* o = reinterpret_cast<float4*>(out + (size_t)(b * NPTS + n) * 12);
        o[0] = make_float4(f0, f1, f2, f3);
        o[1] = make_float4(f4, -f2, f6, f7);     // du/dx = -dv/dy
        o[2] = make_float4(f8, f9, -f8, -f6);    // d2u/dx2 = -d2v/dxdy, d2u/dydx = -d2v/dy2
    }
}

extern "C" void kernel_launch(void* const* d_in, const int* in_sizes, int n_in,
                              void* d_out, int out_size, void* d_ws, size_t ws_size,
                              hipStream_t stream) {
    const float* inp    = (const float*)d_in[0];
    const float* points = (const float*)d_in[1];
    float* out          = (float*)d_out;

    dim3 grid(NPTS / (256 / SPLIT), BATCH);   // 2048 x 4 blocks
    dim3 block(256);
    vortex_features_kernel<<<grid, block, 0, stream>>>(inp, points, out);
}

// Round 3
// 13.382 us; speedup vs baseline: 1.4613x; 1.2091x over previous
//
#include <hip/hip_runtime.h>

#define NPART 64
#define NPTS 32768
#define BATCH 4
#define SPLIT 4                      // threads per point
#define PAIRS (NPART / SPLIT / 2)    // particle-pairs per thread = 8

typedef float f2 __attribute__((ext_vector_type(2)));

__global__ __launch_bounds__(256, 4) void vortex_features_kernel(
    const float* __restrict__ inp,     // [B, NPART, 4] (y, x, tau, sig)
    const float* __restrict__ points,  // [B, NPTS, 2]  (py, px)
    float* __restrict__ out)           // [B, NPTS, 12]
{
    __shared__ float s_y[NPART], s_x[NPART], s_t[NPART], s_i[NPART];

    const int b   = blockIdx.y;
    const int tid = threadIdx.x;

    if (tid < NPART) {
        float4 p = reinterpret_cast<const float4*>(inp)[b * NPART + tid];
        s_y[tid] = p.x;
        s_x[tid] = p.y;
        s_t[tid] = p.z;
        s_i[tid] = 1.0f / (p.w * p.w);
    }
    __syncthreads();

    const int n   = blockIdx.x * (256 / SPLIT) + (tid >> 2);
    const int sub = tid & (SPLIT - 1);

    const float2 pt = reinterpret_cast<const float2*>(points)[b * NPTS + n];
    const float py = pt.x, px = pt.y;

    f2 F0 = 0.f, F1 = 0.f, F2 = 0.f, F3 = 0.f, F4 = 0.f;
    f2 F6 = 0.f, F7 = 0.f, F8 = 0.f, F9 = 0.f;

    const int base = sub * 2;
    #pragma unroll
    for (int ii = 0; ii < PAIRS; ++ii) {
        const int idx = ii * (SPLIT * 2) + base;   // 4-lane group: 8 consecutive floats
        f2 cy = *reinterpret_cast<const f2*>(&s_y[idx]);
        f2 cx = *reinterpret_cast<const f2*>(&s_x[idx]);
        f2 ct = *reinterpret_cast<const f2*>(&s_t[idx]);
        f2 ci = *reinterpret_cast<const f2*>(&s_i[idx]);

        f2 dy  = py - cy;
        f2 dx  = px - cx;
        f2 dy2 = dy * dy;
        f2 dx2 = dx * dx;
        f2 q   = dy2 + dx2;

        f2 rs, e;
        rs.x = __builtin_amdgcn_rsqf(q.x);
        rs.y = __builtin_amdgcn_rsqf(q.y);
        f2 en = q * ci;
        e.x = __expf(-en.x);
        e.y = __expf(-en.y);

        f2 inv_q = rs * rs;                       // 1/q without v_rcp
        f2 g = ct * e * rs;                       // tau e / r
        f2 a = -(ci + 0.5f * inv_q);              // g'/g
        f2 h = g * a;                             // g'
        f2 k = g * (a * a + 0.5f * (inv_q * inv_q));  // g''
        f2 h2 = h + h;
        f2 h6 = 6.0f * h;
        f2 k4 = 4.0f * k;
        f2 A = k4 * dy2;
        f2 B = k4 * dx2;

        F0 += g * dx;                 // v
        F1 -= g * dy;                 // u
        F2 += h2 * (dy * dx);         // dv/dy
        F3 += h2 * dx2 + g;           // dv/dx
        F4 -= h2 * dy2 + g;           // du/dy
        F6 += dx * (A + h2);          // d2v/dy2
        F7 += dx * (B + h6);          // d2v/dx2
        F8 += dy * (B + h2);          // d2v/dxdy
        F9 -= dy * (A + h6);          // d2u/dy2
    }

    // horizontal add of the packed halves
    float f0 = F0.x + F0.y, f1 = F1.x + F1.y, f2v = F2.x + F2.y;
    float f3 = F3.x + F3.y, f4 = F4.x + F4.y;
    float f6 = F6.x + F6.y, f7 = F7.x + F7.y;
    float f8 = F8.x + F8.y, f9 = F9.x + F9.y;

    // reduce across the 4 lanes sharing a point
    #pragma unroll
    for (int m = 1; m <= 2; m <<= 1) {
        f0  += __shfl_xor(f0, m);
        f1  += __shfl_xor(f1, m);
        f2v += __shfl_xor(f2v, m);
        f3  += __shfl_xor(f3, m);
        f4  += __shfl_xor(f4, m);
        f6  += __shfl_xor(f6, m);
        f7  += __shfl_xor(f7, m);
        f8  += __shfl_xor(f8, m);
        f9  += __shfl_xor(f9, m);
    }

    if (sub == 0) {
        float4* o = reinterpret_cast<float4*>(out + (size_t)(b * NPTS + n) * 12);
        o[0] = make_float4(f0, f1, f2v, f3);
        o[1] = make_float4(f4, -f2v, f6, f7);     // du/dx = -dv/dy
        o[2] = make_float4(f8, f9, -f8, -f6);     // d2u/dx2 = -d2v/dxdy, d2u/dydx = -d2v/dy2
    }
}

extern "C" void kernel_launch(void* const* d_in, const int* in_sizes, int n_in,
                              void* d_out, int out_size, void* d_ws, size_t ws_size,
                              hipStream_t stream) {
    const float* inp    = (const float*)d_in[0];
    const float* points = (const float*)d_in[1];
    float* out          = (float*)d_out;

    dim3 grid(NPTS / (256 / SPLIT), BATCH);   // 2048 x 4 blocks
    dim3 block(256);
    vortex_features_kernel<<<grid, block, 0, stream>>>(inp, points, out);
}

// Round 4
// 12.982 us; speedup vs baseline: 1.5064x; 1.0308x over previous
//
#include <hip/hip_runtime.h>

#define NPART 64
#define NPTS 32768
#define BATCH 4
#define SPLIT 4                      // threads per point
#define PAIRS (NPART / SPLIT / 2)    // particle-pairs per thread = 8

typedef float f2 __attribute__((ext_vector_type(2)));

__global__ __launch_bounds__(256, 6) void vortex_features_kernel(
    const float* __restrict__ inp,     // [B, NPART, 4] (y, x, tau, sig)
    const float* __restrict__ points,  // [B, NPTS, 2]  (py, px)
    float* __restrict__ out)           // [B, NPTS, 12]
{
    __shared__ float s_y[NPART], s_x[NPART], s_t[NPART], s_i[NPART];

    const int b   = blockIdx.y;
    const int tid = threadIdx.x;

    if (tid < NPART) {
        float4 p = reinterpret_cast<const float4*>(inp)[b * NPART + tid];
        s_y[tid] = p.x;
        s_x[tid] = p.y;
        s_t[tid] = p.z;
        s_i[tid] = 1.0f / (p.w * p.w);
    }
    __syncthreads();

    const int n   = blockIdx.x * (256 / SPLIT) + (tid >> 2);
    const int sub = tid & (SPLIT - 1);

    const float2 pt = reinterpret_cast<const float2*>(points)[b * NPTS + n];
    const float py = pt.x, px = pt.y;

    // 12 linear moments (hp = -h = -g', kk = g''):
    f2 F0 = 0.f, F1 = 0.f, Sg = 0.f, S1 = 0.f, S2 = 0.f;
    f2 V1 = 0.f, W1 = 0.f, P  = 0.f;
    f2 U1 = 0.f, U2 = 0.f, U3 = 0.f, U4 = 0.f;

    const int base = sub * 2;
    #pragma unroll
    for (int ii = 0; ii < PAIRS; ++ii) {
        const int idx = ii * (SPLIT * 2) + base;   // 4-lane group: 8 consecutive floats
        f2 cy = *reinterpret_cast<const f2*>(&s_y[idx]);
        f2 cx = *reinterpret_cast<const f2*>(&s_x[idx]);
        f2 ct = *reinterpret_cast<const f2*>(&s_t[idx]);
        f2 ci = *reinterpret_cast<const f2*>(&s_i[idx]);

        f2 dy  = py - cy;
        f2 dx  = px - cx;
        f2 dy2 = dy * dy;
        f2 dx2 = dx * dx;
        f2 q   = dy2 + dx2;
        f2 en  = q * ci;

        f2 rs, e;
        rs.x = __builtin_amdgcn_rsqf(q.x);
        rs.y = __builtin_amdgcn_rsqf(q.y);
        e.x = __expf(-en.x);
        e.y = __expf(-en.y);

        f2 inv_q = rs * rs;                    // 1/q
        f2 ge = ct * e;
        f2 g  = ge * rs;                       // g  = tau e / r
        f2 ap = 0.5f * inv_q + ci;             // -g'/g
        f2 hp = g * ap;                        // -g' = -h
        f2 a2 = ap * ap;
        f2 iq2 = inv_q * inv_q;
        f2 kk = g * (0.5f * iq2 + a2);         // g'' = k
        f2 kdx = kk * dx;
        f2 kdy = kk * dy;
        f2 dydx = dy * dx;

        F0 += g * dx;        // Σ g dx
        F1 += g * dy;        // Σ g dy
        Sg += g;             // Σ g
        S1 += hp * dx2;      // -Σ h dx²
        S2 += hp * dy2;      // -Σ h dy²
        V1 += hp * dx;       // -Σ h dx
        W1 += hp * dy;       // -Σ h dy
        P  += hp * dydx;     // -Σ h dy dx
        U1 += kdy * dydx;    // Σ k dy² dx
        U2 += kdx * dx2;     // Σ k dx³
        U3 += kdx * dydx;    // Σ k dx² dy
        U4 += kdy * dy2;     // Σ k dy³
    }

    // horizontal add of packed halves, then assemble the 9 independent
    // features per-thread (linear in moments), THEN cross-lane reduce.
    float sF0 = F0.x + F0.y, sF1 = F1.x + F1.y, sSg = Sg.x + Sg.y;
    float sS1 = S1.x + S1.y, sS2 = S2.x + S2.y;
    float sV1 = V1.x + V1.y, sW1 = W1.x + W1.y, sP = P.x + P.y;
    float sU1 = U1.x + U1.y, sU2 = U2.x + U2.y;
    float sU3 = U3.x + U3.y, sU4 = U4.x + U4.y;

    float f0  = sF0;                       // v
    float f1  = -sF1;                      // u
    float f2v = -2.0f * sP;                // dv/dy
    float f3  = sSg - 2.0f * sS1;          // dv/dx
    float f4  = 2.0f * sS2 - sSg;          // du/dy
    float f6  = 4.0f * sU1 - 2.0f * sV1;   // d2v/dy2
    float f7  = 4.0f * sU2 - 6.0f * sV1;   // d2v/dx2
    float f8  = 4.0f * sU3 - 2.0f * sW1;   // d2v/dxdy
    float f9  = 6.0f * sW1 - 4.0f * sU4;   // d2u/dy2

    #pragma unroll
    for (int m = 1; m <= 2; m <<= 1) {
        f0  += __shfl_xor(f0, m);
        f1  += __shfl_xor(f1, m);
        f2v += __shfl_xor(f2v, m);
        f3  += __shfl_xor(f3, m);
        f4  += __shfl_xor(f4, m);
        f6  += __shfl_xor(f6, m);
        f7  += __shfl_xor(f7, m);
        f8  += __shfl_xor(f8, m);
        f9  += __shfl_xor(f9, m);
    }

    if (sub == 0) {
        float4* o = reinterpret_cast<float4*>(out + (size_t)(b * NPTS + n) * 12);
        o[0] = make_float4(f0, f1, f2v, f3);
        o[1] = make_float4(f4, -f2v, f6, f7);     // du/dx = -dv/dy
        o[2] = make_float4(f8, f9, -f8, -f6);     // d2u/dx2 = -d2v/dxdy, d2u/dydx = -d2v/dy2
    }
}

extern "C" void kernel_launch(void* const* d_in, const int* in_sizes, int n_in,
                              void* d_out, int out_size, void* d_ws, size_t ws_size,
                              hipStream_t stream) {
    const float* inp    = (const float*)d_in[0];
    const float* points = (const float*)d_in[1];
    float* out          = (float*)d_out;

    dim3 grid(NPTS / (256 / SPLIT), BATCH);   // 512 x 4 blocks
    dim3 block(256);
    vortex_features_kernel<<<grid, block, 0, stream>>>(inp, points, out);
}